// Round 14
// baseline (34.436 us; speedup 1.0000x reference)
//
#include <hip/hip_runtime.h>

#define D 64
#define STR 72    // LDS row stride in bf16 elems
#define WAVES 4   // waves per block, each wave independent

typedef __attribute__((ext_vector_type(8))) short bf16x8;
typedef __attribute__((ext_vector_type(4))) float f32x4;
typedef __attribute__((ext_vector_type(4))) unsigned int u32x4;

static __device__ __forceinline__ unsigned short f2bf(float f) {
  unsigned u = __builtin_bit_cast(unsigned, f);
  u += 0x7fffu + ((u >> 16) & 1u);  // RNE
  return (unsigned short)(u >> 16);
}

// wave-private LDS ordering macro (also pins compiler vs aliasing rewrites)
#define LDSWAIT() asm volatile("s_waitcnt lgkmcnt(0)" ::: "memory")

// DPP (VALU-pipe) 16-lane reduction steps — r11-verified encodings:
//   0xB1 quad_perm xor1, 0x4E quad_perm xor2, 0x124 row_ror:4, 0x128 row_ror:8
#define DPP_MOV(x, ctrl)                                                     \
  __builtin_bit_cast(float, __builtin_amdgcn_update_dpp(                     \
      0, __builtin_bit_cast(int, x), (ctrl), 0xf, 0xf, true))

// r14: r11 body verbatim, but each wave serially processes a BALANCED PAIR of
// sequences (pattern positions q and 6-q (or 7 for q=3): L1+L2 == 80 always).
// 2048 waves / 512 blocks -> 8 waves/CU CONSTANT to kernel end (no drain tail,
// which the occupancy counter fingered as the r4-r13 plateau). Mapping
// wid = b + 512*w gives all waves of a block the same q -> uniform blocks.
__global__ __launch_bounds__(256, 4)
void seq_attn_kernel(const float* __restrict__ h,
                     const int* __restrict__ sse,  // int32 (JAX x64 disabled)
                     float* __restrict__ out) {
  __shared__ unsigned short HsAll[WAVES * 64 * STR];  // 36.9 KB/block

  const int tid = threadIdx.x;
  const int w = tid >> 6;
  const int lane = tid & 63;
  unsigned short* Hs = HsAll + w * (64 * STR);  // wave-private slice

  const int wid = blockIdx.x + 512 * w;   // 0..2047
  const int k = wid >> 2;                  // 8-seq pattern group, 0..511
  const int q = wid & 3;                   // position in group (uniform per block)
  const int base = k * 8;
  const int s1 = base + q;                           // L in {16,24,32,40}
  const int s2 = base + ((q < 3) ? (6 - q) : 7);     // L in {64,56,48,40}
  const int g = lane >> 4;
  const int c16 = lane & 15;

  #pragma unroll 1
  for (int it2 = 0; it2 < 2; ++it2) {
    const int s = (it2 == 0) ? s1 : s2;
    const int start = sse[2 * s];
    const int L = sse[2 * s + 1] - start;
    const int nt = (L + 15) >> 4;  // live 16-row tiles

    LDSWAIT();  // seq2 staging must not pass seq1's outstanding LDS reads

    // ---- stage H fp32->bf16 (r11 verbatim): all 64 rows written, pads zero ----
    {
      const float* src = h + (size_t)start * D;
      const int c4 = c16 * 4;
      float4 va[8], vb[8];
      #pragma unroll
      for (int it = 0; it < 8; ++it) {
        const int r = it * 4 + g;
        const int rc = (r < L) ? r : 0;
        va[it] = *(const float4*)(src + rc * D + c4);
      }
      const bool hi = (L > 32);
      #pragma unroll
      for (int it = 0; it < 8; ++it) {
        const int r = 32 + it * 4 + g;
        const int rc = (r < L) ? r : 0;
        vb[it] = hi ? *(const float4*)(src + rc * D + c4) : make_float4(0.f, 0.f, 0.f, 0.f);
      }
      #pragma unroll
      for (int it = 0; it < 8; ++it) {
        const int r = it * 4 + g;
        const bool ok = (r < L);
        ushort4 wv;
        wv.x = ok ? f2bf(va[it].x) : (unsigned short)0;
        wv.y = ok ? f2bf(va[it].y) : (unsigned short)0;
        wv.z = ok ? f2bf(va[it].z) : (unsigned short)0;
        wv.w = ok ? f2bf(va[it].w) : (unsigned short)0;
        *(ushort4*)&Hs[r * STR + c4] = wv;
      }
      #pragma unroll
      for (int it = 0; it < 8; ++it) {
        const int r = 32 + it * 4 + g;
        const bool ok = (r < L);
        ushort4 wv;
        wv.x = ok ? f2bf(vb[it].x) : (unsigned short)0;
        wv.y = ok ? f2bf(vb[it].y) : (unsigned short)0;
        wv.z = ok ? f2bf(vb[it].z) : (unsigned short)0;
        wv.w = ok ? f2bf(vb[it].w) : (unsigned short)0;
        *(ushort4*)&Hs[r * STR + c4] = wv;
      }
    }
    LDSWAIT();  // staging ds_writes drained before fragment reads

    // ---- hf: A-layout fragments (both operands of S = H H^T) ----
    bf16x8 hf[4][2];
    #pragma unroll
    for (int t = 0; t < 4; ++t)
      #pragma unroll
      for (int kb = 0; kb < 2; ++kb)
        hf[t][kb] = *(const bf16x8*)&Hs[(t * 16 + c16) * STR + kb * 32 + g * 8];

    // ---- vf: B-layout fragments for PV, preloaded BEFORE P overwrites Hs ----
    bf16x8 vf[4][2];
    #pragma unroll
    for (int t = 0; t < 4; ++t)
      #pragma unroll
      for (int kb = 0; kb < 2; ++kb) {
        u32x4 wv;
        #pragma unroll
        for (int dd = 0; dd < 4; ++dd) {
          const int k0 = kb * 32 + g * 8 + 2 * dd;
          const unsigned lo = Hs[k0 * STR + t * 16 + c16];
          const unsigned hi2 = Hs[(k0 + 1) * STR + t * 16 + c16];
          wv[dd] = lo | (hi2 << 16);
        }
        vf[t][kb] = __builtin_bit_cast(bf16x8, wv);
      }

    // ---- per 16-row tile: QK^T -> softmax(DPP) -> P restage -> PV -> store ----
    #pragma unroll
    for (int ti = 0; ti < 4; ++ti) {
      if (ti >= nt) continue;  // wave-uniform

      f32x4 acc[4];
      #pragma unroll
      for (int tj = 0; tj < 4; ++tj) {
        f32x4 z = {0.f, 0.f, 0.f, 0.f};
        acc[tj] = z;
      }
      #pragma unroll
      for (int tj = 0; tj < 4; ++tj)
        #pragma unroll
        for (int kb = 0; kb < 2; ++kb)
          acc[tj] = __builtin_amdgcn_mfma_f32_16x16x32_bf16(
              hf[ti][kb], hf[tj][kb], acc[tj], 0, 0, 0);

      // softmax over keys. C layout: row = 16*ti + 4*g + r, col = 16*tj + c16.
      float inv[4];
      #pragma unroll
      for (int r = 0; r < 4; ++r) {
        float mx = -1e30f;
        #pragma unroll
        for (int tj = 0; tj < 4; ++tj) {
          const float sv = (tj * 16 + c16 < L) ? acc[tj][r] : -1e30f;
          acc[tj][r] = sv;
          mx = fmaxf(mx, sv);
        }
        mx = fmaxf(mx, DPP_MOV(mx, 0xB1));   // quad_perm xor1
        mx = fmaxf(mx, DPP_MOV(mx, 0x4E));   // quad_perm xor2
        mx = fmaxf(mx, DPP_MOV(mx, 0x124));  // row_ror:4
        mx = fmaxf(mx, DPP_MOV(mx, 0x128));  // row_ror:8
        float sum = 0.f;
        #pragma unroll
        for (int tj = 0; tj < 4; ++tj) {
          const float p = __expf(acc[tj][r] - mx);
          acc[tj][r] = p;
          sum += p;
        }
        sum += DPP_MOV(sum, 0xB1);
        sum += DPP_MOV(sum, 0x4E);
        sum += DPP_MOV(sum, 0x124);
        sum += DPP_MOV(sum, 0x128);
        inv[r] = 1.0f / sum;  // normalization deferred to epilogue
      }

      // P tile (bf16) into Hs rows [16*ti, 16*ti+16) — tile-disjoint, no WAR
      #pragma unroll
      for (int tj = 0; tj < 4; ++tj)
        #pragma unroll
        for (int r = 0; r < 4; ++r)
          Hs[(ti * 16 + g * 4 + r) * STR + tj * 16 + c16] = f2bf(acc[tj][r]);

      LDSWAIT();  // order ds_write(P) -> ds_read(pf) within the wave

      bf16x8 pf[2];
      #pragma unroll
      for (int kb = 0; kb < 2; ++kb)
        pf[kb] = *(const bf16x8*)&Hs[(ti * 16 + c16) * STR + kb * 32 + g * 8];

      f32x4 o[4];
      #pragma unroll
      for (int tjd = 0; tjd < 4; ++tjd) {
        f32x4 z = {0.f, 0.f, 0.f, 0.f};
        o[tjd] = z;
      }
      #pragma unroll
      for (int tjd = 0; tjd < 4; ++tjd)
        #pragma unroll
        for (int kb = 0; kb < 2; ++kb)
          o[tjd] = __builtin_amdgcn_mfma_f32_16x16x32_bf16(
              pf[kb], vf[tjd][kb], o[tjd], 0, 0, 0);

      #pragma unroll
      for (int r = 0; r < 4; ++r) {
        const int row = ti * 16 + g * 4 + r;
        if (row < L) {
          float* dst = out + (size_t)(start + row) * D;
          const float sc = inv[r];
          #pragma unroll
          for (int tjd = 0; tjd < 4; ++tjd)
            dst[tjd * 16 + c16] = o[tjd][r] * sc;
        }
      }
    }
  }
}

extern "C" void kernel_launch(void* const* d_in, const int* in_sizes, int n_in,
                              void* d_out, int out_size, void* d_ws, size_t ws_size,
                              hipStream_t stream) {
  const float* h = (const float*)d_in[0];
  const int* sse = (const int*)d_in[1];
  float* out = (float*)d_out;
  // 4096 seqs -> 2048 balanced pair-waves -> 512 blocks of 4 waves
  seq_attn_kernel<<<512, 64 * WAVES, 0, stream>>>(h, sse, out);
}